// Round 15
// baseline (6317.899 us; speedup 1.0000x reference)
//
#include <hip/hip_runtime.h>
#include <stdint.h>

#define BDIM 256
#define SEQL 128
#define IND 512
#define HID 512
#define KDIM 1024 // IND + HID

typedef __bf16 bf16x8 __attribute__((ext_vector_type(8)));
typedef float floatx4 __attribute__((ext_vector_type(4)));
typedef _Float16 f16x8 __attribute__((ext_vector_type(8)));

__device__ __forceinline__ float sigm(float x) { return 1.0f / (1.0f + __expf(-x)); }

__device__ __forceinline__ ushort f2bf(float v) {
  uint32_t x = __builtin_bit_cast(uint32_t, v);
  x += 0x7fffu + ((x >> 16) & 1u);
  return (ushort)(x >> 16);
}
__device__ __forceinline__ float bf2f(ushort u) {
  return __builtin_bit_cast(float, ((uint32_t)u) << 16);
}

// ---- one-time: W -> bf16 hi/lo in [4H][IN|HID] row-major; combined bias ----
__global__ __launch_bounds__(256) void k_wconv(
    const float* __restrict__ W_ih, const float* __restrict__ W_hh,
    const float* __restrict__ b_ih, const float* __restrict__ b_hh,
    ushort* __restrict__ Whi, ushort* __restrict__ Wlo, float* __restrict__ bias) {
  int row = blockIdx.x;
  if (threadIdx.x == 0) bias[row] = b_ih[row] + b_hh[row];
  for (int k = threadIdx.x; k < KDIM; k += 256) {
    float w = (k < IND) ? W_ih[(size_t)row * IND + k] : W_hh[(size_t)row * HID + (k - IND)];
    ushort hi = f2bf(w);
    Whi[(size_t)row * KDIM + k] = hi;
    Wlo[(size_t)row * KDIM + k] = f2bf(w - bf2f(hi));
  }
}

// ---- init: h0,c0 from the zero-input zero-state cell (gates = bias) ----
__global__ void k_init(const float* __restrict__ b_ih, const float* __restrict__ b_hh,
                       float* __restrict__ c, ushort* __restrict__ Ahi, ushort* __restrict__ Alo) {
  int b = blockIdx.x;
  for (int j = threadIdx.x; j < HID; j += blockDim.x) {
    float bi = b_ih[j] + b_hh[j];
    float bg = b_ih[2 * HID + j] + b_hh[2 * HID + j];
    float bo = b_ih[3 * HID + j] + b_hh[3 * HID + j];
    float c0 = sigm(bi) * tanhf(bg);
    float h0 = sigm(bo) * tanhf(c0);
    c[b * HID + j] = c0;
    ushort hi = f2bf(h0);
    Ahi[(size_t)b * KDIM + IND + j] = hi;
    Alo[(size_t)b * KDIM + IND + j] = f2bf(h0 - bf2f(hi));
  }
}

// Shared layout: x (fp16) pinned for the whole kernel + phase-scratch union.
// 131072 + 27136 = 158208 B = 154.5 KiB (<= 160 KiB/CU; m201 precedent 128 KiB).
struct __align__(16) StepS {
  _Float16 sx[SEQL][IND];                  // 131072 B, resident all 128 steps
  union {
    struct { float sl[SEQL]; float sxi[4][HID]; } a;                    // 8704 B
    struct { ushort sA[2][16][72]; ushort sW[2][64][72]; float sR[4][16][16]; } g; // 27136 B
  } u;
};

// 16-block group sync (R13-proven, bit-exact there): monotonic counter,
// release-add / relaxed-spin / one acquire. Max value 2*16*128 = 4096.
__device__ __forceinline__ void gsync(unsigned* cnt, unsigned target) {
  __syncthreads();
  if (threadIdx.x == 0) {
    __hip_atomic_fetch_add(cnt, 1u, __ATOMIC_RELEASE, __HIP_MEMORY_SCOPE_AGENT);
    while (__hip_atomic_load(cnt, __ATOMIC_RELAXED, __HIP_MEMORY_SCOPE_AGENT) < target)
      __builtin_amdgcn_s_sleep(2);
    (void)__hip_atomic_load(cnt, __ATOMIC_ACQUIRE, __HIP_MEMORY_SCOPE_AGENT);
  }
  __syncthreads();
}

// single-buffer gates staging (R1-proven reg-prefetch pattern, R9 wave map)
#define SBLOAD(KO) do { \
  Pa  = *(const uint4*)(gA + (KO)); \
  Pw0 = *(const uint4*)(gWhi + (KO)); Pw1 = *(const uint4*)(gWhi + (KO) + 8); \
  Pw2 = *(const uint4*)(gWlo + (KO)); Pw3 = *(const uint4*)(gWlo + (KO) + 8); } while (0)
#define SBSTORE() do { \
  *(uint4*)&S.u.g.sA[sthalf][ar][ac] = Pa; \
  *(uint4*)&S.u.g.sW[0][wr][wc] = Pw0; *(uint4*)&S.u.g.sW[0][wr][wc + 8] = Pw1; \
  *(uint4*)&S.u.g.sW[1][wr][wc] = Pw2; *(uint4*)&S.u.g.sW[1][wr][wc + 8] = Pw3; } while (0)
#define SBCOMPUTE() do { \
  _Pragma("unroll") for (int ks = 0; ks < 2; ++ks) { \
    int kb = ks * 32 + koff; \
    bf16x8 ah = *(const bf16x8*)(&S.u.g.sA[0][ml][kb]); \
    bf16x8 al = *(const bf16x8*)(&S.u.g.sA[1][ml][kb]); \
    bf16x8 wh = *(const bf16x8*)(&S.u.g.sW[0][g * 16 + ml][kb]); \
    bf16x8 wl = *(const bf16x8*)(&S.u.g.sW[1][g * 16 + ml][kb]); \
    accA = __builtin_amdgcn_mfma_f32_16x16x32_bf16(ah, wh, accA, 0, 0, 0); \
    accB = __builtin_amdgcn_mfma_f32_16x16x32_bf16(ah, wl, accB, 0, 0, 0); \
    accB = __builtin_amdgcn_mfma_f32_16x16x32_bf16(al, wh, accB, 0, 0, 0); } } while (0)

// Persistent fused step loop: x-in-LDS kills the 26 MB/step HBM re-fetch
// (R13 counters: dur ~= hbm_bytes / 600 GB/s -> step was x-fetch-bound;
// per-XCD x working set 4.19 MB vs 4.0 MB L2 = streaming thrash).
__global__ __launch_bounds__(256) void k_persist(
    const float* __restrict__ x, const float* __restrict__ Wa,
    const float* __restrict__ ba, float* __restrict__ c,
    const ushort* __restrict__ Whi, const ushort* __restrict__ Wlo,
    const float* __restrict__ bias,
    ushort* __restrict__ A0hi, ushort* __restrict__ A0lo,
    ushort* __restrict__ A1hi, ushort* __restrict__ A1lo,
    float* __restrict__ out, unsigned* __restrict__ bar) {
  __shared__ StepS S;
  int blk = blockIdx.x, tid = threadIdx.x;
  int lane = tid & 63, wave = tid >> 6;
  // R13-proven decode: XCD n owns j-tiles 4n..4n+3; group bt = 16 blocks.
  int n = blk & 7, s = blk >> 3;
  int bt = s & 15, psel = s >> 4;
  int b0 = bt * 16;
  int myb = b0 + 2 * n + psel;
  int j0a = (4 * n + 2 * psel) * 16;
  unsigned* gcnt = bar + bt * 16;

  // ---- prologue: x[myb] fp32 -> fp16 -> LDS (once; read from HBM once) ----
  {
    const float* xb = x + (size_t)myb * SEQL * IND;
    _Float16* sxf = &S.sx[0][0];
    for (int i = 0; i < 32; ++i) {
      size_t o = (size_t)i * 2048 + (size_t)tid * 8;
      float4 v0 = *(const float4*)(xb + o);
      float4 v1 = *(const float4*)(xb + o + 4);
      f16x8 h;
      h[0] = (_Float16)v0.x; h[1] = (_Float16)v0.y; h[2] = (_Float16)v0.z; h[3] = (_Float16)v0.w;
      h[4] = (_Float16)v1.x; h[5] = (_Float16)v1.y; h[6] = (_Float16)v1.z; h[7] = (_Float16)v1.w;
      *(f16x8*)(sxf + o) = h;
    }
  }
  __syncthreads();

  // gates-phase thread constants (R9/R14 map)
  int sthalf = tid >> 7;
  int ar = (tid & 127) >> 3, ac = (tid & 7) * 8;
  int wr = tid >> 2, wc = (tid & 3) * 16;
  int g = tid >> 6, ml = lane & 15, koff = (lane >> 4) * 8;
  int jj = tid & 15, bb = tid >> 4;

  for (int t = 0; t < SEQL; ++t) {
    ushort* Rhi = (t & 1) ? A1hi : A0hi;
    ushort* Rlo = (t & 1) ? A1lo : A0lo;
    ushort* Dhi = (t & 1) ? A0hi : A1hi;
    ushort* Dlo = (t & 1) ? A0lo : A1lo;

    // ================= ATTN (R12 math, x from LDS) =================
    {
      float4 c0 = *(const float4*)(c + (size_t)myb * HID + lane * 4);
      float4 c1 = *(const float4*)(c + (size_t)myb * HID + lane * 4 + 256);
#pragma unroll 4
      for (int si = 0; si < 32; ++si) {
        int ss = wave * 32 + si;
        const float4* wr4 = (const float4*)(Wa + (size_t)ss * HID);
        float4 w0 = wr4[lane];
        float4 w1 = wr4[lane + 64];
        float acc = c0.x * w0.x + c0.y * w0.y + c0.z * w0.z + c0.w * w0.w
                  + c1.x * w1.x + c1.y * w1.y + c1.z * w1.z + c1.w * w1.w;
#pragma unroll
        for (int off = 32; off > 0; off >>= 1) acc += __shfl_down(acc, off);
        if (lane == 0) S.u.a.sl[ss] = acc + ba[ss];
      }
      __syncthreads();
      if (tid < 64) {
        float v0 = S.u.a.sl[tid], v1 = S.u.a.sl[tid + 64];
        float m = fmaxf(v0, v1);
#pragma unroll
        for (int off = 32; off > 0; off >>= 1) m = fmaxf(m, __shfl_xor(m, off));
        float e0 = __expf(v0 - m), e1 = __expf(v1 - m);
        float s2 = e0 + e1;
#pragma unroll
        for (int off = 32; off > 0; off >>= 1) s2 += __shfl_xor(s2, off);
        float inv = 1.f / s2;
        S.u.a.sl[tid] = e0 * inv; S.u.a.sl[tid + 64] = e1 * inv;
      }
      __syncthreads();
      int cix = tid & 63, qp = tid >> 6;
      const _Float16* xrow = &S.sx[qp * 32][8 * cix];
      float a0 = 0.f, a1 = 0.f, a2 = 0.f, a3 = 0.f, a4 = 0.f, a5 = 0.f, a6 = 0.f, a7 = 0.f;
#pragma unroll 8
      for (int ss = 0; ss < 32; ++ss) {
        float w = S.u.a.sl[qp * 32 + ss];
        f16x8 v = *(const f16x8*)(xrow + (size_t)ss * IND);
        a0 += w * (float)v[0]; a1 += w * (float)v[1];
        a2 += w * (float)v[2]; a3 += w * (float)v[3];
        a4 += w * (float)v[4]; a5 += w * (float)v[5];
        a6 += w * (float)v[6]; a7 += w * (float)v[7];
      }
      *(float4*)(&S.u.a.sxi[qp][8 * cix])     = (float4){a0, a1, a2, a3};
      *(float4*)(&S.u.a.sxi[qp][8 * cix + 4]) = (float4){a4, a5, a6, a7};
      __syncthreads();
      float rx = S.u.a.sxi[0][2 * tid] + S.u.a.sxi[1][2 * tid] + S.u.a.sxi[2][2 * tid] + S.u.a.sxi[3][2 * tid];
      float ry = S.u.a.sxi[0][2 * tid + 1] + S.u.a.sxi[1][2 * tid + 1] + S.u.a.sxi[2][2 * tid + 1] + S.u.a.sxi[3][2 * tid + 1];
      ushort hx = f2bf(rx), hy = f2bf(ry);
      uint hp = (uint)hx | ((uint)hy << 16);
      uint lp = (uint)f2bf(rx - bf2f(hx)) | ((uint)f2bf(ry - bf2f(hy)) << 16);
      *(uint*)(Rhi + (size_t)myb * KDIM + 2 * tid) = hp;
      *(uint*)(Rlo + (size_t)myb * KDIM + 2 * tid) = lp;
    }
    gsync(gcnt, 32u * (unsigned)t + 16u);

    // ========= GATES: 2 j-tiles sequential (R9 body, single-buffer) =========
#pragma unroll 1
    for (int t2 = 0; t2 < 2; ++t2) {
      int j0 = j0a + 16 * t2;
      const ushort* gA = (sthalf ? Rlo : Rhi) + (size_t)(b0 + ar) * KDIM + ac;
      int wrow = (wr >> 4) * HID + j0 + (wr & 15);
      const ushort* gWhi = Whi + (size_t)wrow * KDIM + wc;
      const ushort* gWlo = Wlo + (size_t)wrow * KDIM + wc;
      floatx4 accA = {0.f, 0.f, 0.f, 0.f}, accB = {0.f, 0.f, 0.f, 0.f};
      uint4 Pa, Pw0, Pw1, Pw2, Pw3;
      SBLOAD(0);
      for (int k0 = 0; k0 < 16; ++k0) {
        SBSTORE();
        __syncthreads();
        if (k0 + 1 < 16) SBLOAD((k0 + 1) * 64);
        SBCOMPUTE();
        __syncthreads();
      }
      {
        floatx4 acc = accA + accB;
#pragma unroll
        for (int r = 0; r < 4; ++r) S.u.g.sR[g][ml][(lane >> 4) * 4 + r] = acc[r];
      }
      __syncthreads();
      {
        int jg = j0 + jj, b = b0 + bb;
        float ig = sigm(S.u.g.sR[0][jj][bb] + bias[jg]);
        float fg = sigm(S.u.g.sR[1][jj][bb] + bias[HID + jg]);
        float gg = tanhf(S.u.g.sR[2][jj][bb] + bias[2 * HID + jg]);
        float og = sigm(S.u.g.sR[3][jj][bb] + bias[3 * HID + jg]);
        float co = c[(size_t)b * HID + jg];
        float cn = fg * co + ig * gg;
        float hv = og * tanhf(cn);
        c[(size_t)b * HID + jg] = cn;
        out[((size_t)b * SEQL + t) * HID + jg] = hv;
        ushort hi = f2bf(hv);
        Dhi[(size_t)b * KDIM + IND + jg] = hi;
        Dlo[(size_t)b * KDIM + IND + jg] = f2bf(hv - bf2f(hi));
      }
      __syncthreads();
    }
    gsync(gcnt, 32u * (unsigned)t + 32u);
  }
}

extern "C" void kernel_launch(void* const* d_in, const int* in_sizes, int n_in,
                              void* d_out, int out_size, void* d_ws, size_t ws_size,
                              hipStream_t stream) {
  (void)in_sizes; (void)n_in; (void)out_size; (void)ws_size;
  const float* x    = (const float*)d_in[0];
  const float* W_ih = (const float*)d_in[1];
  const float* W_hh = (const float*)d_in[2];
  const float* b_ih = (const float*)d_in[3];
  const float* b_hh = (const float*)d_in[4];
  const float* Wa   = (const float*)d_in[5];
  const float* ba   = (const float*)d_in[6];
  float* out = (float*)d_out;

  // ws footprint: ~13 MiB
  char* p = (char*)d_ws;
  auto carve = [&](size_t bytes) { char* r = p; p += (bytes + 255) & ~(size_t)255; return r; };
  unsigned* bar = (unsigned*)carve(1024);  // 16 group counters, 64B apart
  float*  c    = (float*)carve((size_t)BDIM * HID * 4);
  float*  bias = (float*)carve((size_t)4 * HID * 4);
  ushort* Whi  = (ushort*)carve((size_t)4 * HID * KDIM * 2);
  ushort* Wlo  = (ushort*)carve((size_t)4 * HID * KDIM * 2);
  ushort* A0hi = (ushort*)carve((size_t)BDIM * KDIM * 2);
  ushort* A0lo = (ushort*)carve((size_t)BDIM * KDIM * 2);
  ushort* A1hi = (ushort*)carve((size_t)BDIM * KDIM * 2);
  ushort* A1lo = (ushort*)carve((size_t)BDIM * KDIM * 2);

  hipMemsetAsync(bar, 0, 1024, stream);
  k_wconv<<<4 * HID, 256, 0, stream>>>(W_ih, W_hh, b_ih, b_hh, Whi, Wlo, bias);
  k_init<<<BDIM, 256, 0, stream>>>(b_ih, b_hh, c, A0hi, A0lo);
  k_persist<<<BDIM, 256, 0, stream>>>(x, Wa, ba, c, Whi, Wlo, bias,
                                      A0hi, A0lo, A1hi, A1lo, out, bar);
}

// Round 16
// 5262.088 us; speedup vs baseline: 1.2006x; 1.2006x over previous
//
#include <hip/hip_runtime.h>
#include <stdint.h>

#define BDIM 256
#define SEQL 128
#define IND 512
#define HID 512
#define KDIM 1024 // IND + HID

typedef __bf16 bf16x8 __attribute__((ext_vector_type(8)));
typedef float floatx4 __attribute__((ext_vector_type(4)));
typedef _Float16 f16x8 __attribute__((ext_vector_type(8)));

__device__ __forceinline__ float sigm(float x) { return 1.0f / (1.0f + __expf(-x)); }

__device__ __forceinline__ ushort f2bf(float v) {
  uint32_t x = __builtin_bit_cast(uint32_t, v);
  x += 0x7fffu + ((x >> 16) & 1u);
  return (ushort)(x >> 16);
}
__device__ __forceinline__ float bf2f(ushort u) {
  return __builtin_bit_cast(float, ((uint32_t)u) << 16);
}

// ---- one-time: W -> bf16 hi/lo in [4H][IN|HID] row-major; combined bias ----
__global__ __launch_bounds__(256) void k_wconv(
    const float* __restrict__ W_ih, const float* __restrict__ W_hh,
    const float* __restrict__ b_ih, const float* __restrict__ b_hh,
    ushort* __restrict__ Whi, ushort* __restrict__ Wlo, float* __restrict__ bias) {
  int row = blockIdx.x;
  if (threadIdx.x == 0) bias[row] = b_ih[row] + b_hh[row];
  for (int k = threadIdx.x; k < KDIM; k += 256) {
    float w = (k < IND) ? W_ih[(size_t)row * IND + k] : W_hh[(size_t)row * HID + (k - IND)];
    ushort hi = f2bf(w);
    Whi[(size_t)row * KDIM + k] = hi;
    Wlo[(size_t)row * KDIM + k] = f2bf(w - bf2f(hi));
  }
}

// ---- one-time: x -> fp16 (R12-proven) ----
__global__ __launch_bounds__(256) void k_xconv(const float* __restrict__ x,
                                               _Float16* __restrict__ xh) {
  size_t i = ((size_t)blockIdx.x * 256 + threadIdx.x) * 8;
  float4 v0 = *(const float4*)(x + i);
  float4 v1 = *(const float4*)(x + i + 4);
  f16x8 o;
  o[0] = (_Float16)v0.x; o[1] = (_Float16)v0.y; o[2] = (_Float16)v0.z; o[3] = (_Float16)v0.w;
  o[4] = (_Float16)v1.x; o[5] = (_Float16)v1.y; o[6] = (_Float16)v1.z; o[7] = (_Float16)v1.w;
  *(f16x8*)(xh + i) = o;
}

// ---- init: h0,c0 from the zero-input zero-state cell (gates = bias) ----
__global__ void k_init(const float* __restrict__ b_ih, const float* __restrict__ b_hh,
                       float* __restrict__ c, ushort* __restrict__ Ahi, ushort* __restrict__ Alo) {
  int b = blockIdx.x;
  for (int j = threadIdx.x; j < HID; j += blockDim.x) {
    float bi = b_ih[j] + b_hh[j];
    float bg = b_ih[2 * HID + j] + b_hh[2 * HID + j];
    float bo = b_ih[3 * HID + j] + b_hh[3 * HID + j];
    float c0 = sigm(bi) * tanhf(bg);
    float h0 = sigm(bo) * tanhf(c0);
    c[b * HID + j] = c0;
    ushort hi = f2bf(h0);
    Ahi[(size_t)b * KDIM + IND + j] = hi;
    Alo[(size_t)b * KDIM + IND + j] = f2bf(h0 - bf2f(hi));
  }
}

struct AttnS { float sl[SEQL]; float sxi[4][HID]; };           // 8.7 KB
struct GemmS {
  ushort sA[2][2][16][72];   // [buf][hi/lo][batch][k] 9 KB
  ushort sW[2][2][64][72];   // [buf][hi/lo][row][k] 36 KB
  float  sR[4][16][16];      // gate exchange 4 KB
};
union SU { AttnS a; GemmS g; };  // 49 KB -> exactly 3 blocks/CU (768 = 256x3)

// GEMM staging/compute (R9/R14-proven v3 body): split accA/accB chains
#define G3LOAD(R, KO) do { \
  R##a  = *(const uint4*)(gA + (KO)); \
  R##w0 = *(const uint4*)(gWhi + (KO));      R##w1 = *(const uint4*)(gWhi + (KO) + 8);  \
  R##w2 = *(const uint4*)(gWlo + (KO));      R##w3 = *(const uint4*)(gWlo + (KO) + 8);  } while (0)
#define G3STORE(BUF, R) do { \
  *(uint4*)&su.g.sA[BUF][sthalf][ar][ac] = R##a; \
  *(uint4*)&su.g.sW[BUF][0][wr][wc] = R##w0;  *(uint4*)&su.g.sW[BUF][0][wr][wc + 8] = R##w1; \
  *(uint4*)&su.g.sW[BUF][1][wr][wc] = R##w2;  *(uint4*)&su.g.sW[BUF][1][wr][wc + 8] = R##w3; } while (0)
#define G3COMPUTE(BUF) do { \
  _Pragma("unroll") for (int ks = 0; ks < 2; ++ks) { \
    int kb = ks * 32 + koff; \
    bf16x8 ah = *(const bf16x8*)(&su.g.sA[BUF][0][ml][kb]); \
    bf16x8 al = *(const bf16x8*)(&su.g.sA[BUF][1][ml][kb]); \
    bf16x8 wh = *(const bf16x8*)(&su.g.sW[BUF][0][g * 16 + ml][kb]); \
    bf16x8 wl = *(const bf16x8*)(&su.g.sW[BUF][1][g * 16 + ml][kb]); \
    accA = __builtin_amdgcn_mfma_f32_16x16x32_bf16(ah, wh, accA, 0, 0, 0); \
    accB = __builtin_amdgcn_mfma_f32_16x16x32_bf16(ah, wl, accB, 0, 0, 0); \
    accB = __builtin_amdgcn_mfma_f32_16x16x32_bf16(al, wh, accB, 0, 0, 0); } } while (0)
#define G3LOOP(NCH) \
  G3LOAD(A, 0); G3LOAD(B, 64); \
  G3STORE(0, A); G3STORE(1, B); \
  G3LOAD(A, 128); G3LOAD(B, 192); \
  __syncthreads(); \
  for (int k0 = 0; k0 < (NCH); k0 += 2) { \
    G3COMPUTE(0); \
    __syncthreads(); \
    if (k0 + 2 < (NCH)) { G3STORE(0, A); if (k0 + 4 < (NCH)) G3LOAD(A, (k0 + 4) * 64); } \
    G3COMPUTE(1); \
    __syncthreads(); \
    if (k0 + 3 < (NCH)) { G3STORE(1, B); if (k0 + 5 < (NCH)) G3LOAD(B, (k0 + 5) * 64); } \
  }

// One step, one kernel, 768 blocks (3/CU -- all co-resident by capacity):
//   blocks 0..255:  attn(batch) -> xi -> flag[bt] += 1 (release)
//   blocks 256..767: gatesH (K=[512,1024), dep only on t-1; overlaps attn)
//                    -> wait flag[bt] >= 16(t+1) -> gatesX (K=[0,512))
//                    continuing SAME accumulators (P round-trip eliminated)
//                    -> fused cell epilogue.
// R15 falsified traffic-bound theory (FETCH 5x lower, same 49 us/step);
// the lever is co-resident concurrency (R9/R14) -- this keeps R14's 3/CU
// overlap and removes 1 launch + 4 MB/step of P traffic.
__global__ __launch_bounds__(256) void k_step(
    float* __restrict__ c, const float* __restrict__ Wa,
    const float* __restrict__ ba, const _Float16* __restrict__ xh,
    const ushort* __restrict__ Whi, const ushort* __restrict__ Wlo,
    const float* __restrict__ bias,
    ushort* __restrict__ Rhi, ushort* __restrict__ Rlo,
    ushort* __restrict__ Dhi, ushort* __restrict__ Dlo,
    float* __restrict__ out, unsigned* __restrict__ flag, int t) {
  __shared__ __align__(16) SU su;
  int blk = blockIdx.x, tid = threadIdx.x;
  int lane = tid & 63, wave = tid >> 6;
  int n = blk & 7, s = blk >> 3;

  if (s < 32) {
    // ================= ATTN (R12-proven body), batch = s*8+n =============
    int b = s * 8 + n;
    float4 c0 = *(const float4*)(c + (size_t)b * HID + lane * 4);
    float4 c1 = *(const float4*)(c + (size_t)b * HID + lane * 4 + 256);
#pragma unroll 4
    for (int si = 0; si < 32; ++si) {
      int ss = wave * 32 + si;
      const float4* wr4 = (const float4*)(Wa + (size_t)ss * HID);
      float4 w0 = wr4[lane];
      float4 w1 = wr4[lane + 64];
      float acc = c0.x * w0.x + c0.y * w0.y + c0.z * w0.z + c0.w * w0.w
                + c1.x * w1.x + c1.y * w1.y + c1.z * w1.z + c1.w * w1.w;
#pragma unroll
      for (int off = 32; off > 0; off >>= 1) acc += __shfl_down(acc, off);
      if (lane == 0) su.a.sl[ss] = acc + ba[ss];
    }
    __syncthreads();
    if (tid < 64) {
      float v0 = su.a.sl[tid], v1 = su.a.sl[tid + 64];
      float m = fmaxf(v0, v1);
#pragma unroll
      for (int off = 32; off > 0; off >>= 1) m = fmaxf(m, __shfl_xor(m, off));
      float e0 = __expf(v0 - m), e1 = __expf(v1 - m);
      float s2 = e0 + e1;
#pragma unroll
      for (int off = 32; off > 0; off >>= 1) s2 += __shfl_xor(s2, off);
      float inv = 1.f / s2;
      su.a.sl[tid] = e0 * inv; su.a.sl[tid + 64] = e1 * inv;
    }
    __syncthreads();
    int cix = tid & 63, qp = tid >> 6;
    const _Float16* xrow = xh + (size_t)b * SEQL * IND + (size_t)qp * 32 * IND + 8 * cix;
    float a0 = 0.f, a1 = 0.f, a2 = 0.f, a3 = 0.f, a4 = 0.f, a5 = 0.f, a6 = 0.f, a7 = 0.f;
#pragma unroll 8
    for (int ss = 0; ss < 32; ++ss) {
      float w = su.a.sl[qp * 32 + ss];
      f16x8 v = *(const f16x8*)(xrow + (size_t)ss * IND);
      a0 += w * (float)v[0]; a1 += w * (float)v[1];
      a2 += w * (float)v[2]; a3 += w * (float)v[3];
      a4 += w * (float)v[4]; a5 += w * (float)v[5];
      a6 += w * (float)v[6]; a7 += w * (float)v[7];
    }
    *(float4*)(&su.a.sxi[qp][8 * cix])     = (float4){a0, a1, a2, a3};
    *(float4*)(&su.a.sxi[qp][8 * cix + 4]) = (float4){a4, a5, a6, a7};
    __syncthreads();
    float rx = su.a.sxi[0][2 * tid] + su.a.sxi[1][2 * tid] + su.a.sxi[2][2 * tid] + su.a.sxi[3][2 * tid];
    float ry = su.a.sxi[0][2 * tid + 1] + su.a.sxi[1][2 * tid + 1] + su.a.sxi[2][2 * tid + 1] + su.a.sxi[3][2 * tid + 1];
    ushort hx = f2bf(rx), hy = f2bf(ry);
    uint hp = (uint)hx | ((uint)hy << 16);
    uint lp = (uint)f2bf(rx - bf2f(hx)) | ((uint)f2bf(ry - bf2f(hy)) << 16);
    *(uint*)(Rhi + (size_t)b * KDIM + 2 * tid) = hp;
    *(uint*)(Rlo + (size_t)b * KDIM + 2 * tid) = lp;
    // signal: xi[b] ready (syncthreads drains each wave's stores to L2;
    // release-RMW flushes L2 -> globally visible; R3-proven chain)
    __syncthreads();
    if (tid == 0)
      __hip_atomic_fetch_add(flag + (b >> 4) * 16, 1u, __ATOMIC_RELEASE, __HIP_MEMORY_SCOPE_AGENT);
  } else {
    // ============ gatesH -> wait -> gatesX -> epilogue ====================
    int q = s - 32;            // 0..63 per-XCD tile index
    int jt = 4 * n + (q & 3);  // j-tile (XCD-local W slice, R9 map)
    int bt = q >> 2;           // batch-tile 0..15
    int j0 = jt * 16, b0 = bt * 16;
    int sthalf = tid >> 7;
    int ar = (tid & 127) >> 3, ac = (tid & 7) * 8;
    int wr = tid >> 2, wc = (tid & 3) * 16;
    int g = tid >> 6, ml = lane & 15, koff = (lane >> 4) * 8;
    int wrow = (wr >> 4) * HID + j0 + (wr & 15);

    floatx4 accA = {0.f, 0.f, 0.f, 0.f}, accB = {0.f, 0.f, 0.f, 0.f};
    uint4 Aa, Aw0, Aw1, Aw2, Aw3, Ba, Bw0, Bw1, Bw2, Bw3;

    // ---- gatesH: K=[512,1024) -- depends only on step t-1's h ----
    const ushort* gA  = (sthalf ? Rlo : Rhi) + (size_t)(b0 + ar) * KDIM + IND + ac;
    const ushort* gWhi = Whi + (size_t)wrow * KDIM + IND + wc;
    const ushort* gWlo = Wlo + (size_t)wrow * KDIM + IND + wc;
    G3LOOP(8)

    // ---- wait for this group's 16 attn producers ----
    if (tid == 0) {
      while (__hip_atomic_load(flag + bt * 16, __ATOMIC_RELAXED, __HIP_MEMORY_SCOPE_AGENT)
             < 16u * (unsigned)(t + 1))
        __builtin_amdgcn_s_sleep(2);
      (void)__hip_atomic_load(flag + bt * 16, __ATOMIC_ACQUIRE, __HIP_MEMORY_SCOPE_AGENT);
    }
    __syncthreads();

    // ---- gatesX: K=[0,512), same accumulators (no P round-trip) ----
    gA  = (sthalf ? Rlo : Rhi) + (size_t)(b0 + ar) * KDIM + ac;
    gWhi = Whi + (size_t)wrow * KDIM + wc;
    gWlo = Wlo + (size_t)wrow * KDIM + wc;
    G3LOOP(8)

    {
      floatx4 acc = accA + accB;
#pragma unroll
      for (int r = 0; r < 4; ++r) su.g.sR[g][ml][(lane >> 4) * 4 + r] = acc[r];
    }
    __syncthreads();
    {
      int jj = tid & 15, bb = tid >> 4;
      int jg = j0 + jj, b = b0 + bb;
      float ig = sigm(su.g.sR[0][jj][bb] + bias[jg]);
      float fg = sigm(su.g.sR[1][jj][bb] + bias[HID + jg]);
      float gg = tanhf(su.g.sR[2][jj][bb] + bias[2 * HID + jg]);
      float og = sigm(su.g.sR[3][jj][bb] + bias[3 * HID + jg]);
      float co = c[(size_t)b * HID + jg];
      float cn = fg * co + ig * gg;
      float hv = og * tanhf(cn);
      c[(size_t)b * HID + jg] = cn;
      out[((size_t)b * SEQL + t) * HID + jg] = hv;
      ushort hi = f2bf(hv);
      Dhi[(size_t)b * KDIM + IND + jg] = hi;
      Dlo[(size_t)b * KDIM + IND + jg] = f2bf(hv - bf2f(hi));
    }
  }
}

extern "C" void kernel_launch(void* const* d_in, const int* in_sizes, int n_in,
                              void* d_out, int out_size, void* d_ws, size_t ws_size,
                              hipStream_t stream) {
  (void)in_sizes; (void)n_in; (void)out_size; (void)ws_size;
  const float* x    = (const float*)d_in[0];
  const float* W_ih = (const float*)d_in[1];
  const float* W_hh = (const float*)d_in[2];
  const float* b_ih = (const float*)d_in[3];
  const float* b_hh = (const float*)d_in[4];
  const float* Wa   = (const float*)d_in[5];
  const float* ba   = (const float*)d_in[6];
  float* out = (float*)d_out;

  // ws footprint: ~45 MiB
  char* p = (char*)d_ws;
  auto carve = [&](size_t bytes) { char* r = p; p += (bytes + 255) & ~(size_t)255; return r; };
  unsigned* flag = (unsigned*)carve(1024);  // 16 group flags, 64B apart
  float*  c    = (float*)carve((size_t)BDIM * HID * 4);
  float*  bias = (float*)carve((size_t)4 * HID * 4);
  ushort* Whi  = (ushort*)carve((size_t)4 * HID * KDIM * 2);
  ushort* Wlo  = (ushort*)carve((size_t)4 * HID * KDIM * 2);
  ushort* A0hi = (ushort*)carve((size_t)BDIM * KDIM * 2);
  ushort* A0lo = (ushort*)carve((size_t)BDIM * KDIM * 2);
  ushort* A1hi = (ushort*)carve((size_t)BDIM * KDIM * 2);
  ushort* A1lo = (ushort*)carve((size_t)BDIM * KDIM * 2);
  _Float16* xh = (_Float16*)carve((size_t)BDIM * SEQL * IND * 2);

  hipMemsetAsync(flag, 0, 1024, stream);
  k_wconv<<<4 * HID, 256, 0, stream>>>(W_ih, W_hh, b_ih, b_hh, Whi, Wlo, bias);
  k_xconv<<<(BDIM * SEQL * IND) / (256 * 8), 256, 0, stream>>>(x, xh);
  k_init<<<BDIM, 256, 0, stream>>>(b_ih, b_hh, c, A0hi, A0lo);

  for (int t = 0; t < SEQL; ++t) {
    ushort* Rhi = (t & 1) ? A1hi : A0hi;
    ushort* Rlo = (t & 1) ? A1lo : A0lo;
    ushort* Dhi = (t & 1) ? A0hi : A1hi;
    ushort* Dlo = (t & 1) ? A0lo : A1lo;
    k_step<<<768, 256, 0, stream>>>(c, Wa, ba, xh, Whi, Wlo, bias,
                                    Rhi, Rlo, Dhi, Dlo, out, flag, t);
  }
}

// Round 18
// 4351.205 us; speedup vs baseline: 1.4520x; 1.2093x over previous
//
#include <hip/hip_runtime.h>
#include <stdint.h>

#define BDIM 256
#define SEQL 128
#define IND 512
#define HID 512
#define KDIM 1024 // IND + HID

typedef __bf16 bf16x8 __attribute__((ext_vector_type(8)));
typedef float floatx4 __attribute__((ext_vector_type(4)));
typedef _Float16 f16x8 __attribute__((ext_vector_type(8)));

__device__ __forceinline__ float sigm(float x) { return 1.0f / (1.0f + __expf(-x)); }

__device__ __forceinline__ ushort f2bf(float v) {
  uint32_t x = __builtin_bit_cast(uint32_t, v);
  x += 0x7fffu + ((x >> 16) & 1u);
  return (ushort)(x >> 16);
}
__device__ __forceinline__ float bf2f(ushort u) {
  return __builtin_bit_cast(float, ((uint32_t)u) << 16);
}

// ---- one-time: W -> bf16 hi/lo in [4H][IN|HID] row-major; combined bias ----
__global__ __launch_bounds__(256) void k_wconv(
    const float* __restrict__ W_ih, const float* __restrict__ W_hh,
    const float* __restrict__ b_ih, const float* __restrict__ b_hh,
    ushort* __restrict__ Whi, ushort* __restrict__ Wlo, float* __restrict__ bias) {
  int row = blockIdx.x;
  if (threadIdx.x == 0) bias[row] = b_ih[row] + b_hh[row];
  for (int k = threadIdx.x; k < KDIM; k += 256) {
    float w = (k < IND) ? W_ih[(size_t)row * IND + k] : W_hh[(size_t)row * HID + (k - IND)];
    ushort hi = f2bf(w);
    Whi[(size_t)row * KDIM + k] = hi;
    Wlo[(size_t)row * KDIM + k] = f2bf(w - bf2f(hi));
  }
}

// ---- one-time: x -> fp16 (R12-proven) ----
__global__ __launch_bounds__(256) void k_xconv(const float* __restrict__ x,
                                               _Float16* __restrict__ xh) {
  size_t i = ((size_t)blockIdx.x * 256 + threadIdx.x) * 8;
  float4 v0 = *(const float4*)(x + i);
  float4 v1 = *(const float4*)(x + i + 4);
  f16x8 o;
  o[0] = (_Float16)v0.x; o[1] = (_Float16)v0.y; o[2] = (_Float16)v0.z; o[3] = (_Float16)v0.w;
  o[4] = (_Float16)v1.x; o[5] = (_Float16)v1.y; o[6] = (_Float16)v1.z; o[7] = (_Float16)v1.w;
  *(f16x8*)(xh + i) = o;
}

// ---- init: h0,c0 from the zero-input zero-state cell (gates = bias) ----
__global__ void k_init(const float* __restrict__ b_ih, const float* __restrict__ b_hh,
                       float* __restrict__ c, ushort* __restrict__ Ahi, ushort* __restrict__ Alo) {
  int b = blockIdx.x;
  for (int j = threadIdx.x; j < HID; j += blockDim.x) {
    float bi = b_ih[j] + b_hh[j];
    float bg = b_ih[2 * HID + j] + b_hh[2 * HID + j];
    float bo = b_ih[3 * HID + j] + b_hh[3 * HID + j];
    float c0 = sigm(bi) * tanhf(bg);
    float h0 = sigm(bo) * tanhf(c0);
    c[b * HID + j] = c0;
    ushort hi = f2bf(h0);
    Ahi[(size_t)b * KDIM + IND + j] = hi;
    Alo[(size_t)b * KDIM + IND + j] = f2bf(h0 - bf2f(hi));
  }
}

struct AttnS { float sl[SEQL]; float sxi[4][HID]; };  // ~8.7 KB
struct GemmS {
  ushort sA[2][2][16][72];   // [buf][hi/lo][batch][k] 9 KB
  ushort sW[2][2][64][72];   // [buf][hi/lo][row][k] 36 KB
  float  sR[4][16][16];      // gate exchange 4 KB (k2 only)
};
union SU { AttnS a; GemmS g; };  // ~49 KB -> 3 blocks/CU capacity

// GEMM staging/compute (R9-proven v3 body): split accA/accB chains
#define G3LOAD(R, KO) do { \
  R##a  = *(const uint4*)(gA + (KO)); \
  R##w0 = *(const uint4*)(gWhi + (KO));      R##w1 = *(const uint4*)(gWhi + (KO) + 8);  \
  R##w2 = *(const uint4*)(gWlo + (KO));      R##w3 = *(const uint4*)(gWlo + (KO) + 8);  } while (0)
#define G3STORE(BUF, R) do { \
  *(uint4*)&su.g.sA[BUF][sthalf][ar][ac] = R##a; \
  *(uint4*)&su.g.sW[BUF][0][wr][wc] = R##w0;  *(uint4*)&su.g.sW[BUF][0][wr][wc + 8] = R##w1; \
  *(uint4*)&su.g.sW[BUF][1][wr][wc] = R##w2;  *(uint4*)&su.g.sW[BUF][1][wr][wc + 8] = R##w3; } while (0)
#define G3COMPUTE(BUF) do { \
  _Pragma("unroll") for (int ks = 0; ks < 2; ++ks) { \
    int kb = ks * 32 + koff; \
    bf16x8 ah = *(const bf16x8*)(&su.g.sA[BUF][0][ml][kb]); \
    bf16x8 al = *(const bf16x8*)(&su.g.sA[BUF][1][ml][kb]); \
    bf16x8 wh = *(const bf16x8*)(&su.g.sW[BUF][0][g * 16 + ml][kb]); \
    bf16x8 wl = *(const bf16x8*)(&su.g.sW[BUF][1][g * 16 + ml][kb]); \
    accA = __builtin_amdgcn_mfma_f32_16x16x32_bf16(ah, wh, accA, 0, 0, 0); \
    accB = __builtin_amdgcn_mfma_f32_16x16x32_bf16(ah, wl, accB, 0, 0, 0); \
    accB = __builtin_amdgcn_mfma_f32_16x16x32_bf16(al, wh, accB, 0, 0, 0); } } while (0)
// 8-chunk pipelined K-loop (prologue stages 0,1; loads 2,3 in flight)
#define G3LOOP(NCH) \
  G3LOAD(A, 0); G3LOAD(B, 64); \
  G3STORE(0, A); G3STORE(1, B); \
  G3LOAD(A, 128); G3LOAD(B, 192); \
  __syncthreads(); \
  for (int k0 = 0; k0 < (NCH); k0 += 2) { \
    G3COMPUTE(0); \
    __syncthreads(); \
    if (k0 + 2 < (NCH)) { G3STORE(0, A); if (k0 + 4 < (NCH)) G3LOAD(A, (k0 + 4) * 64); } \
    G3COMPUTE(1); \
    __syncthreads(); \
    if (k0 + 3 < (NCH)) { G3STORE(1, B); if (k0 + 5 < (NCH)) G3LOAD(B, (k0 + 5) * 64); } \
  }

// ---- k1: 768 blocks. Blocks 0..255: attn (xi loop EXPLICITLY software-
// pipelined: two named 8x f16x8 register sets, 16 loads in flight -- R16's
// VGPR=68 showed the compiler-scheduled version held only ~2 loads in flight,
// leaving the xi loop load-latency-serialized; R15 proved traffic is not the
// cost, latency is). Blocks 256..767: gates_h (K half, t-1 dependent),
// overlapping attn (R14-proven). ----
__global__ __launch_bounds__(256) void k1_attn_gatesH(
    const float* __restrict__ c, const float* __restrict__ Wa,
    const float* __restrict__ ba, const _Float16* __restrict__ xh,
    const ushort* __restrict__ Whi, const ushort* __restrict__ Wlo,
    ushort* __restrict__ Rhi, ushort* __restrict__ Rlo,
    float* __restrict__ P) {
  __shared__ __align__(16) SU su;
  int blk = blockIdx.x, tid = threadIdx.x;
  int lane = tid & 63, wave = tid >> 6;

  if (blk < 256) {
    // ================= ATTN =================
    int b = blk;
    float4 c0 = *(const float4*)(c + (size_t)b * HID + lane * 4);
    float4 c1 = *(const float4*)(c + (size_t)b * HID + lane * 4 + 256);
#pragma unroll 4
    for (int si = 0; si < 32; ++si) {
      int s = wave * 32 + si;
      const float4* wr4 = (const float4*)(Wa + (size_t)s * HID);
      float4 w0 = wr4[lane];
      float4 w1 = wr4[lane + 64];
      float acc = c0.x * w0.x + c0.y * w0.y + c0.z * w0.z + c0.w * w0.w
                + c1.x * w1.x + c1.y * w1.y + c1.z * w1.z + c1.w * w1.w;
#pragma unroll
      for (int off = 32; off > 0; off >>= 1) acc += __shfl_down(acc, off);
      if (lane == 0) su.a.sl[s] = acc + ba[s];
    }
    __syncthreads();
    if (tid < 64) {
      float v0 = su.a.sl[tid], v1 = su.a.sl[tid + 64];
      float m = fmaxf(v0, v1);
#pragma unroll
      for (int off = 32; off > 0; off >>= 1) m = fmaxf(m, __shfl_xor(m, off));
      float e0 = __expf(v0 - m), e1 = __expf(v1 - m);
      float s2 = e0 + e1;
#pragma unroll
      for (int off = 32; off > 0; off >>= 1) s2 += __shfl_xor(s2, off);
      float inv = 1.f / s2;
      su.a.sl[tid] = e0 * inv; su.a.sl[tid + 64] = e1 * inv;
    }
    __syncthreads();
    // xi: explicit ping-pong pipeline, 16x 16B loads in flight.
    // Per-accumulator add order is s = 0..31 ascending -- bit-identical R14.
    int cix = tid & 63, qp = tid >> 6;
    const _Float16* xrow = xh + (size_t)b * SEQL * IND + (size_t)qp * 32 * IND + 8 * cix;
    const float* slw = &su.a.sl[qp * 32];
    float a0 = 0.f, a1 = 0.f, a2 = 0.f, a3 = 0.f, a4 = 0.f, a5 = 0.f, a6 = 0.f, a7 = 0.f;
#define XLD(i) (*(const f16x8*)(xrow + (size_t)(i) * IND))
#define XICONSUME(U, W) do { float _w = (W); \
      a0 += _w * (float)(U)[0]; a1 += _w * (float)(U)[1]; \
      a2 += _w * (float)(U)[2]; a3 += _w * (float)(U)[3]; \
      a4 += _w * (float)(U)[4]; a5 += _w * (float)(U)[5]; \
      a6 += _w * (float)(U)[6]; a7 += _w * (float)(U)[7]; } while (0)
    f16x8 p0 = XLD(0),  p1 = XLD(1),  p2 = XLD(2),  p3 = XLD(3);
    f16x8 p4 = XLD(4),  p5 = XLD(5),  p6 = XLD(6),  p7 = XLD(7);
    f16x8 q0 = XLD(8),  q1 = XLD(9),  q2 = XLD(10), q3 = XLD(11);
    f16x8 q4 = XLD(12), q5 = XLD(13), q6 = XLD(14), q7 = XLD(15);
    // consume p(0..7) while q(8..15) in flight
    XICONSUME(p0, slw[0]); XICONSUME(p1, slw[1]); XICONSUME(p2, slw[2]); XICONSUME(p3, slw[3]);
    XICONSUME(p4, slw[4]); XICONSUME(p5, slw[5]); XICONSUME(p6, slw[6]); XICONSUME(p7, slw[7]);
    // issue p(16..23), consume q(8..15)
    p0 = XLD(16); p1 = XLD(17); p2 = XLD(18); p3 = XLD(19);
    p4 = XLD(20); p5 = XLD(21); p6 = XLD(22); p7 = XLD(23);
    XICONSUME(q0, slw[8]);  XICONSUME(q1, slw[9]);  XICONSUME(q2, slw[10]); XICONSUME(q3, slw[11]);
    XICONSUME(q4, slw[12]); XICONSUME(q5, slw[13]); XICONSUME(q6, slw[14]); XICONSUME(q7, slw[15]);
    // issue q(24..31), consume p(16..23)
    q0 = XLD(24); q1 = XLD(25); q2 = XLD(26); q3 = XLD(27);
    q4 = XLD(28); q5 = XLD(29); q6 = XLD(30); q7 = XLD(31);
    XICONSUME(p0, slw[16]); XICONSUME(p1, slw[17]); XICONSUME(p2, slw[18]); XICONSUME(p3, slw[19]);
    XICONSUME(p4, slw[20]); XICONSUME(p5, slw[21]); XICONSUME(p6, slw[22]); XICONSUME(p7, slw[23]);
    // consume q(24..31)
    XICONSUME(q0, slw[24]); XICONSUME(q1, slw[25]); XICONSUME(q2, slw[26]); XICONSUME(q3, slw[27]);
    XICONSUME(q4, slw[28]); XICONSUME(q5, slw[29]); XICONSUME(q6, slw[30]); XICONSUME(q7, slw[31]);
#undef XLD
#undef XICONSUME
    *(float4*)(&su.a.sxi[qp][8 * cix])     = (float4){a0, a1, a2, a3};
    *(float4*)(&su.a.sxi[qp][8 * cix + 4]) = (float4){a4, a5, a6, a7};
    __syncthreads();
    float rx = su.a.sxi[0][2 * tid] + su.a.sxi[1][2 * tid] + su.a.sxi[2][2 * tid] + su.a.sxi[3][2 * tid];
    float ry = su.a.sxi[0][2 * tid + 1] + su.a.sxi[1][2 * tid + 1] + su.a.sxi[2][2 * tid + 1] + su.a.sxi[3][2 * tid + 1];
    ushort hx = f2bf(rx), hy = f2bf(ry);
    uint hp = (uint)hx | ((uint)hy << 16);
    uint lp = (uint)f2bf(rx - bf2f(hx)) | ((uint)f2bf(ry - bf2f(hy)) << 16);
    *(uint*)(Rhi + (size_t)b * KDIM + 2 * tid) = hp;  // xi region: cols 0..511
    *(uint*)(Rlo + (size_t)b * KDIM + 2 * tid) = lp;
  } else {
    // ================= gates_h: K=[512,1024), write P partials ============
    int g2 = blk - 256;                       // (256+g2)%8 == g2%8 -> R9 XCD map
    int lb = (g2 & 7) * 64 + (g2 >> 3);
    int j0 = (lb >> 4) * 16;
    int b0 = (lb & 15) * 16;
    int sthalf = tid >> 7;
    int ar = (tid & 127) >> 3, ac = (tid & 7) * 8;
    const ushort* gA = (sthalf ? Rlo : Rhi) + (size_t)(b0 + ar) * KDIM + IND + ac;  // h region
    int wr = tid >> 2, wc = (tid & 3) * 16;
    int wrow = (wr >> 4) * HID + j0 + (wr & 15);
    const ushort* gWhi = Whi + (size_t)wrow * KDIM + IND + wc;
    const ushort* gWlo = Wlo + (size_t)wrow * KDIM + IND + wc;

    floatx4 accA = {0.f, 0.f, 0.f, 0.f}, accB = {0.f, 0.f, 0.f, 0.f};
    int g = tid >> 6, ml = lane & 15, koff = (lane >> 4) * 8;
    uint4 Aa, Aw0, Aw1, Aw2, Aw3, Ba, Bw0, Bw1, Bw2, Bw3;
    G3LOOP(8)

    // direct P write: tile (g, jt=j0/16, bt=b0/16), [j][b] dense, b fastest.
    floatx4 acc = accA + accB;
    size_t pbase = (((size_t)g * 32 + (j0 >> 4)) * 16 + (b0 >> 4)) * 256;
    *(float4*)(P + pbase + ml * 16 + (lane >> 4) * 4) = *(float4*)&acc;
  }
}

// ---- k2: gates_x -- K=[0,512) (xi) + P + fused cell update. 512 blocks,
// 2/CU (R9-proven TLP), R9 body with half the k-loop.
__global__ __launch_bounds__(256) void k2_gatesX(
    const ushort* __restrict__ Whi, const ushort* __restrict__ Wlo,
    const float* __restrict__ bias, const float* __restrict__ P,
    const ushort* __restrict__ Rhi, const ushort* __restrict__ Rlo,
    float* __restrict__ c, float* __restrict__ out,
    ushort* __restrict__ Dhi, ushort* __restrict__ Dlo, int tstep) {
  __shared__ __align__(16) SU su;
  int bid = blockIdx.x, tid = threadIdx.x;
  int lane = tid & 63;
  int lb = (bid & 7) * 64 + (bid >> 3);
  int j0 = (lb >> 4) * 16;
  int b0 = (lb & 15) * 16;
  int sthalf = tid >> 7;
  int ar = (tid & 127) >> 3, ac = (tid & 7) * 8;
  const ushort* gA = (sthalf ? Rlo : Rhi) + (size_t)(b0 + ar) * KDIM + ac;  // xi region
  int wr = tid >> 2, wc = (tid & 3) * 16;
  int wrow = (wr >> 4) * HID + j0 + (wr & 15);
  const ushort* gWhi = Whi + (size_t)wrow * KDIM + wc;
  const ushort* gWlo = Wlo + (size_t)wrow * KDIM + wc;

  floatx4 accA = {0.f, 0.f, 0.f, 0.f}, accB = {0.f, 0.f, 0.f, 0.f};
  int g = tid >> 6, ml = lane & 15, koff = (lane >> 4) * 8;
  uint4 Aa, Aw0, Aw1, Aw2, Aw3, Ba, Bw0, Bw1, Bw2, Bw3;
  G3LOOP(8)

  {
    floatx4 acc = accA + accB;
#pragma unroll
    for (int r = 0; r < 4; ++r) su.g.sR[g][ml][(lane >> 4) * 4 + r] = acc[r];
  }
  __syncthreads();

  {
    int jj = tid & 15, bb = tid >> 4;
    int jg = j0 + jj;
    int b = b0 + bb;
    size_t pb = (((size_t)(j0 >> 4)) * 16 + (b0 >> 4)) * 256 + jj * 16 + bb;
    const size_t gstr = (size_t)32 * 16 * 256;
    float ig = sigm(su.g.sR[0][jj][bb] + P[pb]            + bias[jg]);
    float fg = sigm(su.g.sR[1][jj][bb] + P[pb + gstr]     + bias[HID + jg]);
    float gg = tanhf(su.g.sR[2][jj][bb] + P[pb + 2 * gstr] + bias[2 * HID + jg]);
    float og = sigm(su.g.sR[3][jj][bb] + P[pb + 3 * gstr] + bias[3 * HID + jg]);
    float co = c[b * HID + jg];
    float cn = fg * co + ig * gg;
    float hv = og * tanhf(cn);
    c[b * HID + jg] = cn;
    out[((size_t)b * SEQL + tstep) * HID + jg] = hv;
    ushort hi = f2bf(hv);
    Dhi[(size_t)b * KDIM + IND + jg] = hi;
    Dlo[(size_t)b * KDIM + IND + jg] = f2bf(hv - bf2f(hi));
  }
}

extern "C" void kernel_launch(void* const* d_in, const int* in_sizes, int n_in,
                              void* d_out, int out_size, void* d_ws, size_t ws_size,
                              hipStream_t stream) {
  (void)in_sizes; (void)n_in; (void)out_size; (void)ws_size;
  const float* x    = (const float*)d_in[0];
  const float* W_ih = (const float*)d_in[1];
  const float* W_hh = (const float*)d_in[2];
  const float* b_ih = (const float*)d_in[3];
  const float* b_hh = (const float*)d_in[4];
  const float* Wa   = (const float*)d_in[5];
  const float* ba   = (const float*)d_in[6];
  float* out = (float*)d_out;

  // ws footprint: ~46 MiB
  char* p = (char*)d_ws;
  auto carve = [&](size_t bytes) { char* r = p; p += (bytes + 255) & ~(size_t)255; return r; };
  float*  c    = (float*)carve((size_t)BDIM * HID * 4);
  float*  bias = (float*)carve((size_t)4 * HID * 4);
  ushort* Whi  = (ushort*)carve((size_t)4 * HID * KDIM * 2);
  ushort* Wlo  = (ushort*)carve((size_t)4 * HID * KDIM * 2);
  ushort* A0hi = (ushort*)carve((size_t)BDIM * KDIM * 2);
  ushort* A0lo = (ushort*)carve((size_t)BDIM * KDIM * 2);
  ushort* A1hi = (ushort*)carve((size_t)BDIM * KDIM * 2);
  ushort* A1lo = (ushort*)carve((size_t)BDIM * KDIM * 2);
  _Float16* xh = (_Float16*)carve((size_t)BDIM * SEQL * IND * 2);
  float*  P    = (float*)carve((size_t)4 * HID * BDIM * 4);  // 2 MB partials

  k_wconv<<<4 * HID, 256, 0, stream>>>(W_ih, W_hh, b_ih, b_hh, Whi, Wlo, bias);
  k_xconv<<<(BDIM * SEQL * IND) / (256 * 8), 256, 0, stream>>>(x, xh);
  k_init<<<BDIM, 256, 0, stream>>>(b_ih, b_hh, c, A0hi, A0lo);

  for (int t = 0; t < SEQL; ++t) {
    ushort* Rhi = (t & 1) ? A1hi : A0hi;
    ushort* Rlo = (t & 1) ? A1lo : A0lo;
    ushort* Dhi = (t & 1) ? A0hi : A1hi;
    ushort* Dlo = (t & 1) ? A0lo : A1lo;
    k1_attn_gatesH<<<768, 256, 0, stream>>>(c, Wa, ba, xh, Whi, Wlo, Rhi, Rlo, P);
    k2_gatesX<<<512, 256, 0, stream>>>(Whi, Wlo, bias, P, Rhi, Rlo, c, out, Dhi, Dlo, t);
  }
}